// Round 2
// baseline (1009.473 us; speedup 1.0000x reference)
//
#include <hip/hip_runtime.h>
#include <math.h>

#define NRES 64
#define NM   50
#define NB   128
#define NL   3
#define NCLS 10

#define PI_D        3.14159265358979323846264338327950288
#define TWO_PI_D    6.28318530717958647692528676655900577
#define INV_2PI_D   0.159154943091895335768883763372514362
#define LAMBDA_D    5.32e-07
#define DIST_D      0.035
#define PLD_D       (PI_D * LAMBDA_D * DIST_D)
#define KD_D        (TWO_PI_D / LAMBDA_D * DIST_D)

// exchange-buffer swizzle: element (r,c) at r*64 + (c ^ PS(r)) -> all four
// transpose access patterns are exactly 2-way (free) on 32 banks.
#define PS(r) ((((r) & 15)) ^ ((((r) & 1)) << 4))
// intensity-buffer swizzle (write natural-per-quad, read row-contiguous)
#define QS(r) ((((r) & 15)) << 1)

__device__ __forceinline__ constexpr int rev4(int i) {
    return ((i & 1) << 3) | ((i & 2) << 1) | ((i & 4) >> 1) | ((i & 8) >> 3);
}

__device__ __forceinline__ float dppx1(float v) {  // lane ^ 1 within quad
    return __int_as_float(__builtin_amdgcn_mov_dpp(__float_as_int(v), 0xB1, 0xF, 0xF, true));
}
__device__ __forceinline__ float dppx2(float v) {  // lane ^ 2 within quad
    return __int_as_float(__builtin_amdgcn_mov_dpp(__float_as_int(v), 0x4E, 0xF, 0xF, true));
}

__device__ __forceinline__ void cmul(float& ar, float& ai, float wr, float wi) {
    float r = ar * wr - ai * wi;
    ai = ar * wi + ai * wr;
    ar = r;
}

// twiddle tables for W16^tw
__device__ __forceinline__ constexpr float c16t(int tw) {
    return (tw == 1) ? 0.923879532511286756f : (tw == 2) ? 0.707106781186547524f :
           (tw == 3) ? 0.382683432365089772f : (tw == 5) ? -0.382683432365089772f :
           (tw == 6) ? -0.707106781186547524f : (tw == 7) ? -0.923879532511286756f : 1.0f;
}
__device__ __forceinline__ constexpr float s16t(int tw) {
    return (tw == 1) ? 0.382683432365089772f : (tw == 2) ? 0.707106781186547524f :
           (tw == 3) ? 0.923879532511286756f : (tw == 5) ? 0.923879532511286756f :
           (tw == 6) ? 0.707106781186547524f : (tw == 7) ? 0.382683432365089772f : 0.0f;
}

// in-place DIF-16, natural input, bit-reversed output (pos i holds X[rev4(i)]).
// forward transform (e^{-i}).
__device__ __forceinline__ void dif16_fwd(float* xr, float* xi) {
#pragma unroll
    for (int len = 8; len >= 1; len >>= 1) {
#pragma unroll
        for (int base = 0; base < 16; base += 2 * len) {
#pragma unroll
            for (int j = 0; j < len; j++) {
                const int i0 = base + j, i1 = i0 + len;
                const int tw = j * (8 / len);
                float ar = xr[i0], ai = xi[i0];
                float br = xr[i1], bi = xi[i1];
                xr[i0] = ar + br; xi[i0] = ai + bi;
                float dr = ar - br, di = ai - bi;
                if (tw == 0)      { xr[i1] = dr;  xi[i1] = di; }
                else if (tw == 4) { xr[i1] = di;  xi[i1] = -dr; }           // * (-i)
                else { xr[i1] = dr * c16t(tw) - di * (-s16t(tw));
                       xi[i1] = dr * (-s16t(tw)) + di * c16t(tw); }
            }
        }
    }
}

// in-place DIT-16, bit-reversed input (pos i holds X[rev4(i)]), natural output.
// inverse transform (e^{+i}), unscaled.
__device__ __forceinline__ void dit16_inv(float* xr, float* xi) {
#pragma unroll
    for (int len = 1; len <= 8; len <<= 1) {
#pragma unroll
        for (int base = 0; base < 16; base += 2 * len) {
#pragma unroll
            for (int j = 0; j < len; j++) {
                const int i0 = base + j, i1 = i0 + len;
                const int tw = j * (8 / len);
                float br = xr[i1], bi = xi[i1];
                if (tw == 4)      { float tp = br; br = -bi; bi = tp; }     // * (+i)
                else if (tw != 0) { float r = br * c16t(tw) - bi * s16t(tw);
                                    bi = br * s16t(tw) + bi * c16t(tw); br = r; }
                float ar = xr[i0], ai = xi[i0];
                xr[i0] = ar + br; xi[i0] = ai + bi;
                xr[i1] = ar - br; xi[i1] = ai - bi;
            }
        }
    }
}

// forward cross-quad 4-pt DFT: stage xor2, lane3 *(-i), stage xor1.
__device__ __forceinline__ void quad_fwd(float* xr, float* xi, int t) {
    const float s2 = (t & 2) ? -1.f : 1.f;
    const float s1 = (t & 1) ? -1.f : 1.f;
    const bool l3 = (t == 3);
#pragma unroll
    for (int i = 0; i < 16; i++) {
        float pr = dppx2(xr[i]), pi = dppx2(xi[i]);
        float r = fmaf(xr[i], s2, pr), m = fmaf(xi[i], s2, pi);
        float r2 = l3 ? m : r, m2 = l3 ? -r : m;      // *(-i) on lane 3
        pr = dppx1(r2); pi = dppx1(m2);
        xr[i] = fmaf(r2, s1, pr); xi[i] = fmaf(m2, s1, pi);
    }
}

// inverse cross-quad 4-pt DFT: stage xor1, lane3 *(+i), stage xor2 (unscaled).
__device__ __forceinline__ void quad_inv(float* xr, float* xi, int t) {
    const float s2 = (t & 2) ? -1.f : 1.f;
    const float s1 = (t & 1) ? -1.f : 1.f;
    const bool l3 = (t == 3);
#pragma unroll
    for (int i = 0; i < 16; i++) {
        float pr = dppx1(xr[i]), pi = dppx1(xi[i]);
        float r = fmaf(xr[i], s1, pr), m = fmaf(xi[i], s1, pi);
        float r2 = l3 ? -m : r, m2 = l3 ? r : m;      // *(+i) on lane 3
        pr = dppx2(r2); pi = dppx2(m2);
        xr[i] = fmaf(r2, s2, pr); xi[i] = fmaf(m2, s2, pi);
    }
}

// full 64-pt forward along the register axis: reg i, lane t -> X[rev4(i)+16*sig]
__device__ __forceinline__ void fwd64(float* xr, float* xi,
                                      const float* w64c, const float* w64s, int t) {
    dif16_fwd(xr, xi);
#pragma unroll
    for (int i = 0; i < 16; i++) {
        const int idx = t * rev4(i);
        cmul(xr[i], xi[i], w64c[idx], -w64s[idx]);
    }
    quad_fwd(xr, xi, t);
}

// full 64-pt inverse (unscaled): input reg i, lane t = X[rev4(i)+16*sig] -> x[4j+t]
__device__ __forceinline__ void inv64(float* xr, float* xi,
                                      const float* w64c, const float* w64s, int t) {
    quad_inv(xr, xi, t);
#pragma unroll
    for (int i = 0; i < 16; i++) {
        const int idx = t * rev4(i);
        cmul(xr[i], xi[i], w64c[idx], w64s[idx]);
    }
    dit16_inv(xr, xi);
}

__global__ __launch_bounds__(256, 4) void donn_main(
    const float* __restrict__ x,
    const float* __restrict__ sre,
    const float* __restrict__ sim,
    const float* __restrict__ phase,
    const float* __restrict__ fcw,
    const float* __restrict__ fcb,
    float* __restrict__ out)
{
    __shared__ float xbr[4096];
    __shared__ float xbi[4096];
    __shared__ float w64c[64], w64s[64];
    __shared__ float hxr[64], hxi[64], hyr[64], hyi[64];

    const int tid = threadIdx.x;
    const int bid = blockIdx.x;
    const int b = bid & (NB - 1);
    const int m = bid >> 7;
    const int g = tid >> 2, t = tid & 3;
    const int sig = ((t & 1) << 1) | (t >> 1);

    if (tid < 64) {
        float ang = (float)tid * (float)(TWO_PI_D / 64.0);
        w64c[tid] = cosf(ang);
        w64s[tid] = sinf(ang);
        double f = (double)((tid < 32) ? tid : tid - 64) * 15625.0;
        double phd = -PLD_D * f * f;
        double r1 = phd - TWO_PI_D * rint(phd * INV_2PI_D);
        hxr[tid] = cosf((float)r1);
        hxi[tid] = sinf((float)r1);
        double phy = phd + KD_D;                      // fold e^{ikD} into Hy
        double r2 = phy - TWO_PI_D * rint(phy * INV_2PI_D);
        hyr[tid] = cosf((float)r2) * (1.0f / 4096.0f);  // fold ifft2 scale
        hyi[tid] = sinf((float)r2) * (1.0f / 4096.0f);
    }

    // stage field = x * screen straight into registers (cols 4j+t of row g)
    float xr[16], xi[16];
    {
        const float* xb = x   + b * 4096 + g * 64 + t;
        const float* sr = sre + m * 4096 + g * 64 + t;
        const float* si = sim + m * 4096 + g * 64 + t;
#pragma unroll
        for (int j = 0; j < 16; j++) {
            float xv = xb[4 * j];
            xr[j] = xv * sr[4 * j];
            xi[j] = xv * si[4 * j];
        }
    }
    __syncthreads();  // tables ready

    const int psg = PS(g);

#pragma unroll 1
    for (int l = 0; l < NL; l++) {
        // multiply exp(i*phase_l) (natural order in regs)
        const float* ph = phase + l * 4096 + g * 64 + t;
#pragma unroll
        for (int j = 0; j < 16; j++) {
            float s, c;
            __sincosf(ph[4 * j], &s, &c);
            cmul(xr[j], xi[j], c, s);
        }
        // FFT along x, * Hx
        fwd64(xr, xi, w64c, w64s, t);
#pragma unroll
        for (int i = 0; i < 16; i++) {
            const int kk = rev4(i) + 16 * sig;
            cmul(xr[i], xi[i], hxr[kk], hxi[kk]);
        }
        // transpose #1: write (row g, col kk), read (col g, natural n)
#pragma unroll
        for (int i = 0; i < 16; i++) {
            const int kk = rev4(i) + 16 * sig;
            const int a = g * 64 + (kk ^ psg);
            xbr[a] = xr[i]; xbi[a] = xi[i];
        }
        __syncthreads();
#pragma unroll
        for (int j = 0; j < 16; j++) {
            const int n = 4 * j + t;
            const int a = n * 64 + (g ^ PS(n));
            xr[j] = xbr[a]; xi[j] = xbi[a];
        }
        __syncthreads();
        // FFT along y, * Hy (incl e^{ikD}, 1/4096), inverse FFT along y -- all in regs
        fwd64(xr, xi, w64c, w64s, t);
#pragma unroll
        for (int i = 0; i < 16; i++) {
            const int kk = rev4(i) + 16 * sig;
            cmul(xr[i], xi[i], hyr[kk], hyi[kk]);
        }
        inv64(xr, xi, w64c, w64s, t);
        // transpose #2: write (natural n, col g), read (row g, col kk)
#pragma unroll
        for (int j = 0; j < 16; j++) {
            const int n = 4 * j + t;
            const int a = n * 64 + (g ^ PS(n));
            xbr[a] = xr[j]; xbi[a] = xi[j];
        }
        __syncthreads();
#pragma unroll
        for (int i = 0; i < 16; i++) {
            const int kk = rev4(i) + 16 * sig;
            const int a = g * 64 + (kk ^ psg);
            xr[i] = xbr[a]; xi[i] = xbi[a];
        }
        __syncthreads();
        // inverse FFT along x -> natural spatial order, ready for next layer
        inv64(xr, xi, w64c, w64s, t);
    }

    // intensity -> LDS (swizzled) for coalesced FC
    const int qsg = QS(g);
#pragma unroll
    for (int j = 0; j < 16; j++) {
        const int c0 = 4 * j + t;
        xbr[g * 64 + (c0 ^ qsg)] = xr[j] * xr[j] + xi[j] * xi[j];
    }
    __syncthreads();

    float ivl[16];
#pragma unroll
    for (int i = 0; i < 16; i++) {
        const int e = i * 256 + tid;
        const int r = e >> 6, c = e & 63;
        ivl[i] = xbr[r * 64 + (c ^ QS(r))];
    }
    float part[NCLS];
#pragma unroll
    for (int c2 = 0; c2 < NCLS; c2++) part[c2] = 0.f;
#pragma unroll
    for (int c2 = 0; c2 < NCLS; c2++) {
        const float* wrow = fcw + c2 * 4096 + tid;
#pragma unroll
        for (int i = 0; i < 16; i++)
            part[c2] = fmaf(ivl[i], wrow[i * 256], part[c2]);
    }
#pragma unroll
    for (int c2 = 0; c2 < NCLS; c2++) {
        float v = part[c2];
#pragma unroll
        for (int off = 32; off >= 1; off >>= 1) v += __shfl_down(v, off);
        if ((tid & 63) == 0) atomicAdd(&out[b * NCLS + c2], v * (1.0f / (float)NM));
    }
    if (m == 0 && tid < NCLS) atomicAdd(&out[b * NCLS + tid], fcb[tid]);
}

extern "C" void kernel_launch(void* const* d_in, const int* in_sizes, int n_in,
                              void* d_out, int out_size, void* d_ws, size_t ws_size,
                              hipStream_t stream) {
    const float* x   = (const float*)d_in[0];
    const float* sre = (const float*)d_in[1];
    const float* sim = (const float*)d_in[2];
    const float* ph  = (const float*)d_in[3];
    const float* fcw = (const float*)d_in[4];
    const float* fcb = (const float*)d_in[5];
    float* out = (float*)d_out;

    hipMemsetAsync(out, 0, (size_t)(NB * NCLS) * sizeof(float), stream);
    donn_main<<<NM * NB, 256, 0, stream>>>(x, sre, sim, ph, fcw, fcb, out);
}

// Round 3
// 406.916 us; speedup vs baseline: 2.4808x; 2.4808x over previous
//
#include <hip/hip_runtime.h>
#include <math.h>

#define NRES 64
#define NM   50
#define NB   128
#define NL   3
#define NCLS 10

#define PI_D        3.14159265358979323846264338327950288
#define TWO_PI_D    6.28318530717958647692528676655900577
#define INV_2PI_D   0.159154943091895335768883763372514362
#define LAMBDA_D    5.32e-07
#define DIST_D      0.035
#define PLD_D       (PI_D * LAMBDA_D * DIST_D)
#define KD_D        (TWO_PI_D / LAMBDA_D * DIST_D)

// exchange-buffer swizzle: element (r,c) at r*64 + (c ^ PS(r)) -> all four
// transpose access patterns are exactly 2-way (free) on 32 banks.
#define PS(r) ((((r) & 15)) ^ ((((r) & 1)) << 4))
// intensity-buffer swizzle (write natural-per-quad, read row-contiguous)
#define QS(r) ((((r) & 15)) << 1)

__device__ __forceinline__ constexpr int rev4(int i) {
    return ((i & 1) << 3) | ((i & 2) << 1) | ((i & 4) >> 1) | ((i & 8) >> 3);
}

__device__ __forceinline__ float dppx1(float v) {  // lane ^ 1 within quad
    return __int_as_float(__builtin_amdgcn_mov_dpp(__float_as_int(v), 0xB1, 0xF, 0xF, true));
}
__device__ __forceinline__ float dppx2(float v) {  // lane ^ 2 within quad
    return __int_as_float(__builtin_amdgcn_mov_dpp(__float_as_int(v), 0x4E, 0xF, 0xF, true));
}

__device__ __forceinline__ void cmul(float& ar, float& ai, float wr, float wi) {
    float r = ar * wr - ai * wi;
    ai = ar * wi + ai * wr;
    ar = r;
}

// twiddle tables for W16^tw
__device__ __forceinline__ constexpr float c16t(int tw) {
    return (tw == 1) ? 0.923879532511286756f : (tw == 2) ? 0.707106781186547524f :
           (tw == 3) ? 0.382683432365089772f : (tw == 5) ? -0.382683432365089772f :
           (tw == 6) ? -0.707106781186547524f : (tw == 7) ? -0.923879532511286756f : 1.0f;
}
__device__ __forceinline__ constexpr float s16t(int tw) {
    return (tw == 1) ? 0.382683432365089772f : (tw == 2) ? 0.707106781186547524f :
           (tw == 3) ? 0.923879532511286756f : (tw == 5) ? 0.923879532511286756f :
           (tw == 6) ? 0.707106781186547524f : (tw == 7) ? 0.382683432365089772f : 0.0f;
}

// in-place DIF-16, natural input, bit-reversed output (pos i holds X[rev4(i)]).
// forward transform (e^{-i}).
__device__ __forceinline__ void dif16_fwd(float* xr, float* xi) {
#pragma unroll
    for (int len = 8; len >= 1; len >>= 1) {
#pragma unroll
        for (int base = 0; base < 16; base += 2 * len) {
#pragma unroll
            for (int j = 0; j < len; j++) {
                const int i0 = base + j, i1 = i0 + len;
                const int tw = j * (8 / len);
                float ar = xr[i0], ai = xi[i0];
                float br = xr[i1], bi = xi[i1];
                xr[i0] = ar + br; xi[i0] = ai + bi;
                float dr = ar - br, di = ai - bi;
                if (tw == 0)      { xr[i1] = dr;  xi[i1] = di; }
                else if (tw == 4) { xr[i1] = di;  xi[i1] = -dr; }           // * (-i)
                else { xr[i1] = dr * c16t(tw) - di * (-s16t(tw));
                       xi[i1] = dr * (-s16t(tw)) + di * c16t(tw); }
            }
        }
    }
}

// in-place DIT-16, bit-reversed input (pos i holds X[rev4(i)]), natural output.
// inverse transform (e^{+i}), unscaled.
__device__ __forceinline__ void dit16_inv(float* xr, float* xi) {
#pragma unroll
    for (int len = 1; len <= 8; len <<= 1) {
#pragma unroll
        for (int base = 0; base < 16; base += 2 * len) {
#pragma unroll
            for (int j = 0; j < len; j++) {
                const int i0 = base + j, i1 = i0 + len;
                const int tw = j * (8 / len);
                float br = xr[i1], bi = xi[i1];
                if (tw == 4)      { float tp = br; br = -bi; bi = tp; }     // * (+i)
                else if (tw != 0) { float r = br * c16t(tw) - bi * s16t(tw);
                                    bi = br * s16t(tw) + bi * c16t(tw); br = r; }
                float ar = xr[i0], ai = xi[i0];
                xr[i0] = ar + br; xi[i0] = ai + bi;
                xr[i1] = ar - br; xi[i1] = ai - bi;
            }
        }
    }
}

// forward cross-quad 4-pt DFT: stage xor2, lane3 *(-i), stage xor1.
__device__ __forceinline__ void quad_fwd(float* xr, float* xi, int t) {
    const float s2 = (t & 2) ? -1.f : 1.f;
    const float s1 = (t & 1) ? -1.f : 1.f;
    const bool l3 = (t == 3);
#pragma unroll
    for (int i = 0; i < 16; i++) {
        float pr = dppx2(xr[i]), pi = dppx2(xi[i]);
        float r = fmaf(xr[i], s2, pr), m = fmaf(xi[i], s2, pi);
        float r2 = l3 ? m : r, m2 = l3 ? -r : m;      // *(-i) on lane 3
        pr = dppx1(r2); pi = dppx1(m2);
        xr[i] = fmaf(r2, s1, pr); xi[i] = fmaf(m2, s1, pi);
    }
}

// inverse cross-quad 4-pt DFT: stage xor1, lane3 *(+i), stage xor2 (unscaled).
__device__ __forceinline__ void quad_inv(float* xr, float* xi, int t) {
    const float s2 = (t & 2) ? -1.f : 1.f;
    const float s1 = (t & 1) ? -1.f : 1.f;
    const bool l3 = (t == 3);
#pragma unroll
    for (int i = 0; i < 16; i++) {
        float pr = dppx1(xr[i]), pi = dppx1(xi[i]);
        float r = fmaf(xr[i], s1, pr), m = fmaf(xi[i], s1, pi);
        float r2 = l3 ? -m : r, m2 = l3 ? r : m;      // *(+i) on lane 3
        pr = dppx2(r2); pi = dppx2(m2);
        xr[i] = fmaf(r2, s2, pr); xi[i] = fmaf(m2, s2, pi);
    }
}

// full 64-pt forward along the register axis: reg i, lane t -> X[rev4(i)+16*sig]
__device__ __forceinline__ void fwd64(float* xr, float* xi,
                                      const float* w64c, const float* w64s, int t) {
    dif16_fwd(xr, xi);
#pragma unroll
    for (int i = 0; i < 16; i++) {
        const int idx = t * rev4(i);
        cmul(xr[i], xi[i], w64c[idx], -w64s[idx]);
    }
    quad_fwd(xr, xi, t);
}

// full 64-pt inverse (unscaled): input reg i, lane t = X[rev4(i)+16*sig] -> x[4j+t]
__device__ __forceinline__ void inv64(float* xr, float* xi,
                                      const float* w64c, const float* w64s, int t) {
    quad_inv(xr, xi, t);
#pragma unroll
    for (int i = 0; i < 16; i++) {
        const int idx = t * rev4(i);
        cmul(xr[i], xi[i], w64c[idx], w64s[idx]);
    }
    dit16_inv(xr, xi);
}

__global__ __launch_bounds__(256) void donn_main(
    const float* __restrict__ x,
    const float* __restrict__ sre,
    const float* __restrict__ sim,
    const float* __restrict__ phase,
    const float* __restrict__ fcw,
    const float* __restrict__ fcb,
    float* __restrict__ out)
{
    __shared__ float xbr[4096];
    __shared__ float xbi[4096];
    __shared__ float w64c[64], w64s[64];
    __shared__ float hxr[64], hxi[64], hyr[64], hyi[64];

    const int tid = threadIdx.x;
    const int bid = blockIdx.x;
    const int b = bid & (NB - 1);
    const int m = bid >> 7;
    const int g = tid >> 2, t = tid & 3;
    const int sig = ((t & 1) << 1) | (t >> 1);

    if (tid < 64) {
        float ang = (float)tid * (float)(TWO_PI_D / 64.0);
        w64c[tid] = cosf(ang);
        w64s[tid] = sinf(ang);
        double f = (double)((tid < 32) ? tid : tid - 64) * 15625.0;
        double phd = -PLD_D * f * f;
        double r1 = phd - TWO_PI_D * rint(phd * INV_2PI_D);
        hxr[tid] = cosf((float)r1);
        hxi[tid] = sinf((float)r1);
        double phy = phd + KD_D;                      // fold e^{ikD} into Hy
        double r2 = phy - TWO_PI_D * rint(phy * INV_2PI_D);
        hyr[tid] = cosf((float)r2) * (1.0f / 4096.0f);  // fold ifft2 scale
        hyi[tid] = sinf((float)r2) * (1.0f / 4096.0f);
    }

    // stage field = x * screen straight into registers (cols 4j+t of row g)
    float xr[16], xi[16];
    {
        const float* xb = x   + b * 4096 + g * 64 + t;
        const float* sr = sre + m * 4096 + g * 64 + t;
        const float* si = sim + m * 4096 + g * 64 + t;
#pragma unroll
        for (int j = 0; j < 16; j++) {
            float xv = xb[4 * j];
            xr[j] = xv * sr[4 * j];
            xi[j] = xv * si[4 * j];
        }
    }
    __syncthreads();  // tables ready

    const int psg = PS(g);

#pragma unroll 1
    for (int l = 0; l < NL; l++) {
        // multiply exp(i*phase_l) (natural order in regs)
        const float* ph = phase + l * 4096 + g * 64 + t;
#pragma unroll
        for (int j = 0; j < 16; j++) {
            float s, c;
            __sincosf(ph[4 * j], &s, &c);
            cmul(xr[j], xi[j], c, s);
        }
        // FFT along x, * Hx
        fwd64(xr, xi, w64c, w64s, t);
#pragma unroll
        for (int i = 0; i < 16; i++) {
            const int kk = rev4(i) + 16 * sig;
            cmul(xr[i], xi[i], hxr[kk], hxi[kk]);
        }
        // transpose #1: write (row g, col kk), read (col g, natural n)
#pragma unroll
        for (int i = 0; i < 16; i++) {
            const int kk = rev4(i) + 16 * sig;
            const int a = g * 64 + (kk ^ psg);
            xbr[a] = xr[i]; xbi[a] = xi[i];
        }
        __syncthreads();
#pragma unroll
        for (int j = 0; j < 16; j++) {
            const int n = 4 * j + t;
            const int a = n * 64 + (g ^ PS(n));
            xr[j] = xbr[a]; xi[j] = xbi[a];
        }
        __syncthreads();
        // FFT along y, * Hy (incl e^{ikD}, 1/4096), inverse FFT along y -- all in regs
        fwd64(xr, xi, w64c, w64s, t);
#pragma unroll
        for (int i = 0; i < 16; i++) {
            const int kk = rev4(i) + 16 * sig;
            cmul(xr[i], xi[i], hyr[kk], hyi[kk]);
        }
        inv64(xr, xi, w64c, w64s, t);
        // transpose #2: write (natural n, col g), read (row g, col kk)
#pragma unroll
        for (int j = 0; j < 16; j++) {
            const int n = 4 * j + t;
            const int a = n * 64 + (g ^ PS(n));
            xbr[a] = xr[j]; xbi[a] = xi[j];
        }
        __syncthreads();
#pragma unroll
        for (int i = 0; i < 16; i++) {
            const int kk = rev4(i) + 16 * sig;
            const int a = g * 64 + (kk ^ psg);
            xr[i] = xbr[a]; xi[i] = xbi[a];
        }
        __syncthreads();
        // inverse FFT along x -> natural spatial order, ready for next layer
        inv64(xr, xi, w64c, w64s, t);
    }

    // intensity -> LDS (swizzled) for coalesced FC
    const int qsg = QS(g);
#pragma unroll
    for (int j = 0; j < 16; j++) {
        const int c0 = 4 * j + t;
        xbr[g * 64 + (c0 ^ qsg)] = xr[j] * xr[j] + xi[j] * xi[j];
    }
    __syncthreads();

    float ivl[16];
#pragma unroll
    for (int i = 0; i < 16; i++) {
        const int e = i * 256 + tid;
        const int r = e >> 6, c = e & 63;
        ivl[i] = xbr[r * 64 + (c ^ QS(r))];
    }
    float part[NCLS];
#pragma unroll
    for (int c2 = 0; c2 < NCLS; c2++) part[c2] = 0.f;
#pragma unroll
    for (int c2 = 0; c2 < NCLS; c2++) {
        const float* wrow = fcw + c2 * 4096 + tid;
#pragma unroll
        for (int i = 0; i < 16; i++)
            part[c2] = fmaf(ivl[i], wrow[i * 256], part[c2]);
    }
#pragma unroll
    for (int c2 = 0; c2 < NCLS; c2++) {
        float v = part[c2];
#pragma unroll
        for (int off = 32; off >= 1; off >>= 1) v += __shfl_down(v, off);
        if ((tid & 63) == 0) atomicAdd(&out[b * NCLS + c2], v * (1.0f / (float)NM));
    }
    if (m == 0 && tid < NCLS) atomicAdd(&out[b * NCLS + tid], fcb[tid]);
}

extern "C" void kernel_launch(void* const* d_in, const int* in_sizes, int n_in,
                              void* d_out, int out_size, void* d_ws, size_t ws_size,
                              hipStream_t stream) {
    const float* x   = (const float*)d_in[0];
    const float* sre = (const float*)d_in[1];
    const float* sim = (const float*)d_in[2];
    const float* ph  = (const float*)d_in[3];
    const float* fcw = (const float*)d_in[4];
    const float* fcb = (const float*)d_in[5];
    float* out = (float*)d_out;

    hipMemsetAsync(out, 0, (size_t)(NB * NCLS) * sizeof(float), stream);
    donn_main<<<NM * NB, 256, 0, stream>>>(x, sre, sim, ph, fcw, fcb, out);
}